// Round 6
// baseline (1556.094 us; speedup 1.0000x reference)
//
#include <hip/hip_runtime.h>
#include <math.h>

#define TT 512
#define DPOI 256
#define DIN 260
#define DHID 356
#define DOUTD 512
#define G3 1536

// GRU partition: 8 worker blocks x 1024 threads, 64 hidden units per block.
// Cross-block comm: agent-scope 4-byte self-validating payloads
// {bf16 h | 16-bit step tag}. Consumers: phase-staggered 2-deep pipelined
// polling. NEW this round: HEATER blocks (blocks GB..GB+GHEAT-1) run dense FMA
// until a done-flag — keeps SCLK at high DVFS state during the latency-bound
// scan (theory: whole graph was running at near-idle clock, inflating every
// latency ~2-3x). Workers/protocol otherwise identical to round 5, plus a fix
// for the poll-loop exit race (stale in-flight load could overwrite pa after
// the pb->pa move; now drained with vmcnt(0) before use).
#define GB 8
#define GHEAT 120
#define HU (DOUTD / GB)      // 64 hidden units per block
#define NRR (3 * HU)         // 192 w_hh rows per block
#define NPAY DOUTD           // 512 dword payload units per step

// ---------------- fused pre-kernel: features + LN + MLP1 + MLP2 + gi ----------------
__global__ __launch_bounds__(512)
void pre_kernel(const int* __restrict__ idx, const float* __restrict__ timef,
                const float* __restrict__ latlon, const float* __restrict__ emb,
                const float* __restrict__ lnw, const float* __restrict__ lnb,
                const float* __restrict__ w1, const float* __restrict__ b1,
                const float* __restrict__ w2, const float* __restrict__ b2,
                const float* __restrict__ wih, const float* __restrict__ bih,
                float* __restrict__ gi, unsigned* __restrict__ hcz,
                unsigned* __restrict__ done) {
    int t = blockIdx.x;
    int tid = threadIdx.x;           // 512 threads
    int wave = tid >> 6, lane = tid & 63;

    __shared__ float xl[DIN];
    __shared__ float h1l[DHID];
    __shared__ alignas(16) float x2l[DPOI];
    __shared__ float red[8];
    __shared__ float mu_s, rs_s;

    // zero this block's slice of hcomm step-tags + the heater done flag
    hcz[(size_t)t * 512 + tid] = 0u;
    if (t == 0 && tid == 0) done[0] = 0u;

    // --- features (redundant per thread; only tid<4 consume) ---
    float tv = fminf(fmaxf(timef[t], 0.f), 1.f);
    const float TWO_PI = 6.28318530717958647692f;
    float f0 = sinf(TWO_PI * tv);
    float f1 = cosf(TWO_PI * tv);
    float f2 = 0.f, f3 = 0.f;
    if (t > 0) {
        float tp = fminf(fmaxf(timef[t - 1], 0.f), 1.f);
        float d = tv - tp;
        d = d - floorf(d);          // jnp.mod(x, 1.0)
        f2 = log1pf(d * 24.f);
        int i0 = idx[t - 1], i1 = idx[t];
        float la0 = latlon[2 * (size_t)i0], lo0 = latlon[2 * (size_t)i0 + 1];
        float la1 = latlon[2 * (size_t)i1], lo1 = latlon[2 * (size_t)i1 + 1];
        const float D2R = 0.01745329251994329577f;
        float lat1 = fminf(fmaxf(la0, -90.f), 90.f) * D2R;
        float lon1 = fminf(fmaxf(lo0, -180.f), 180.f) * D2R;
        float lat2 = fminf(fmaxf(la1, -90.f), 90.f) * D2R;
        float lon2 = fminf(fmaxf(lo1, -180.f), 180.f) * D2R;
        float dlat = (lat2 - lat1) * 0.5f, dlon = (lon2 - lon1) * 0.5f;
        float sdlat = sinf(dlat), sdlon = sinf(dlon);
        float a = sdlat * sdlat +
                  fminf(fmaxf(cosf(lat1), -1.f), 1.f) * fminf(fmaxf(cosf(lat2), -1.f), 1.f) * sdlon * sdlon;
        float aa = fminf(fmaxf(a, 0.f), 1.f);
        float bb = fminf(fmaxf(1.f - a, 1e-12f), 1.f);
        float cc = 2.f * atan2f(sqrtf(aa), sqrtf(bb));
        f3 = log1pf(6371.0088f * cc);
    }
    float fv = (tid == 0) ? f0 : (tid == 1) ? f1 : (tid == 2) ? f2 : f3;

    float v0 = (tid < 256) ? emb[(size_t)idx[t] * DPOI + tid] : 0.f;
    float v1 = (tid < 4) ? fv : 0.f;

    // --- layernorm over 260 elements ---
    float s = v0 + v1;
    for (int o = 32; o; o >>= 1) s += __shfl_down(s, o, 64);
    if (lane == 0) red[wave] = s;
    __syncthreads();
    if (tid == 0) {
        float mm = 0.f;
        for (int i = 0; i < 8; ++i) mm += red[i];
        mu_s = mm * (1.f / 260.f);
    }
    __syncthreads();
    float mu = mu_s;
    float d0 = (tid < 256) ? (v0 - mu) : 0.f;
    float d1 = (tid < 4) ? (v1 - mu) : 0.f;
    float sq = d0 * d0 + d1 * d1;
    for (int o = 32; o; o >>= 1) sq += __shfl_down(sq, o, 64);
    __syncthreads();
    if (lane == 0) red[wave] = sq;
    __syncthreads();
    if (tid == 0) {
        float vv = 0.f;
        for (int i = 0; i < 8; ++i) vv += red[i];
        rs_s = rsqrtf(vv * (1.f / 260.f) + 1e-5f);
    }
    __syncthreads();
    float rs = rs_s;
    if (tid < 256) xl[tid] = d0 * rs * lnw[tid] + lnb[tid];
    if (tid < 4)   xl[256 + tid] = d1 * rs * lnw[256 + tid] + lnb[256 + tid];
    __syncthreads();

    // --- mlp1: x @ w1 + b1, gelu -> h1 (LDS) ---
    if (tid < DHID) {
        float acc = b1[tid];
        #pragma unroll 4
        for (int k = 0; k < DIN; ++k) acc = fmaf(xl[k], w1[k * DHID + tid], acc);
        h1l[tid] = 0.5f * acc * (1.f + erff(acc * 0.70710678118654752440f));
    }
    __syncthreads();

    // --- mlp2: h1 @ w2 + b2 -> x2 (LDS) ---
    if (tid < DPOI) {
        float acc = b2[tid];
        #pragma unroll 4
        for (int k = 0; k < DHID; ++k) acc = fmaf(h1l[k], w2[k * DPOI + tid], acc);
        x2l[tid] = acc;
    }
    __syncthreads();

    // --- gi: x2 @ w_ih.T + b_ih (1536 rows over 8 waves) ---
    float4 xv = ((const float4*)x2l)[lane];
    for (int r = wave; r < G3; r += 8) {
        float4 wv = ((const float4*)(wih + (size_t)r * DPOI))[lane];
        float sd = xv.x * wv.x + xv.y * wv.y + xv.z * wv.z + xv.w * wv.w;
        for (int o = 32; o; o >>= 1) sd += __shfl_down(sd, o, 64);
        if (lane == 0) gi[(size_t)t * G3 + r] = sd + bih[r];
    }
}

// ---------------- GRU scan + clock heaters ----------------
__global__ __launch_bounds__(1024)
void gru_kernel(const float* __restrict__ gi, const float* __restrict__ whh,
                const float* __restrict__ bhh, float* __restrict__ hs,
                unsigned* __restrict__ hcomm, unsigned* __restrict__ done) {
    int tid = threadIdx.x;     // 0..1023

    // ---------- heater path: dense FMA to hold SCLK at high DVFS state ----------
    if (blockIdx.x >= GB) {
        __shared__ unsigned dsh;
        if (tid == 0) dsh = 0u;
        __syncthreads();
        float c0 = (float)(tid + 1) * 1e-6f, c1 = c0 + 0.1f, c2 = c0 + 0.2f, c3 = c0 + 0.3f;
        float c4 = c0 + 0.4f, c5 = c0 + 0.5f, c6 = c0 + 0.6f, c7 = c0 + 0.7f;
        for (int it = 0; it < 8192; ++it) {
            unsigned d = 0;
            if (tid == 0)
                d = __hip_atomic_load(done, __ATOMIC_RELAXED, __HIP_MEMORY_SCOPE_AGENT);
            // 512 FMAs (8 independent chains x 64) — flag load overlaps this
            #pragma unroll 4
            for (int q = 0; q < 64; ++q) {
                c0 = fmaf(c0, 1.0000001f, 1e-7f); c1 = fmaf(c1, 1.0000001f, 1e-7f);
                c2 = fmaf(c2, 1.0000001f, 1e-7f); c3 = fmaf(c3, 1.0000001f, 1e-7f);
                c4 = fmaf(c4, 1.0000001f, 1e-7f); c5 = fmaf(c5, 1.0000001f, 1e-7f);
                c6 = fmaf(c6, 1.0000001f, 1e-7f); c7 = fmaf(c7, 1.0000001f, 1e-7f);
            }
            if (tid == 0 && d) dsh = 1u;
            __syncthreads();
            if (dsh) break;
            __syncthreads();
        }
        asm volatile("" :: "v"(c0), "v"(c1), "v"(c2), "v"(c3),
                           "v"(c4), "v"(c5), "v"(c6), "v"(c7));
        return;
    }

    // ---------- worker path (identical protocol to round 5, race-fixed) ----------
    __shared__ alignas(16) float hprev[DOUTD];   // 2 KB
    __shared__ float gsum[NRR];                  // 768 B

    int b = blockIdx.x;        // 0..7
    int wave = tid >> 6, lane = tid & 63;
    int jbase = b * HU;
    int g4 = lane >> 4, l4 = lane & 15;
    int rr0 = wave * 12 + g4 * 3;      // this lane-group's 3 rows

    // --- W_hh fragments -> f32 registers. Lane covers k = m*64 + l4*4 + {0..3} ---
    float4 wf0[8], wf1[8], wf2[8];
    float bl0, bl1, bl2;
    {
        int r0 = rr0, r1 = rr0 + 1, r2 = rr0 + 2;
        const float4* p0 = (const float4*)(whh + (size_t)((r0 >> 6) * DOUTD + jbase + (r0 & 63)) * DOUTD);
        const float4* p1 = (const float4*)(whh + (size_t)((r1 >> 6) * DOUTD + jbase + (r1 & 63)) * DOUTD);
        const float4* p2 = (const float4*)(whh + (size_t)((r2 >> 6) * DOUTD + jbase + (r2 & 63)) * DOUTD);
        #pragma unroll
        for (int m = 0; m < 8; ++m) {
            wf0[m] = p0[m * 16 + l4];
            wf1[m] = p1[m * 16 + l4];
            wf2[m] = p2[m * 16 + l4];
        }
        bl0 = bhh[(r0 >> 6) * DOUTD + jbase + (r0 & 63)];
        bl1 = bhh[(r1 >> 6) * DOUTD + jbase + (r1 & 63)];
        bl2 = bhh[(r2 >> 6) * DOUTD + jbase + (r2 & 63)];
    }
    if (tid < DOUTD) hprev[tid] = 0.f;
    __syncthreads();

    const float4* hp4 = (const float4*)hprev;
    long budget = 3000;               // lifetime re-entry budget (deadlock -> numeric fail)

    // gi prefetch registers (gate wave only), one step ahead; own h in register.
    float gir = 0.f, giz = 0.f, gin = 0.f, hreg = 0.f;
    if (tid < HU) {
        int j = jbase + tid;
        gir = gi[j];
        giz = gi[DOUTD + j];
        gin = gi[2 * DOUTD + j];
    }

    for (int s = 0; s < TT; ++s) {
        unsigned pa = 0, pb = 0;
        if (s > 0) {
            // waves 4..11 poll: wave (4+wsrc) covers producer block wsrc's 64
            // units; the wave matching our own block skips (self-published).
            if (wave >= 4 && wave < 12 && (wave - 4) != b) {
                int u = ((wave - 4) << 6) + lane;
                const unsigned* ap = hcomm + (size_t)(s - 1) * NPAY + u;
                unsigned tag = (unsigned)s & 0xffffu;   // producer stored ((s-1)+1)
                // prime slot A
                asm volatile("global_load_dword %0, %1, off sc0 sc1"
                             : "=v"(pa) : "v"(ap) : "memory");
                // stagger ~RT/2: dependent FMA chain
                float xx = (float)(lane + 1) * 1e-6f;
                #pragma unroll
                for (int q = 0; q < 256; ++q) xx = fmaf(xx, 1.0000002f, 1.1920929e-7f);
                // prime slot B (chain feeds in as dummy input -> ordered after spin)
                asm volatile("global_load_dword %0, %1, off sc0 sc1"
                             : "=v"(pb) : "v"(ap), "v"(xx) : "memory");
                // 2-deep round-robin pipelined poll; tag-gated; bounded.
                do {
                    unsigned tmp; int scnt;
                    asm volatile(
                        "s_movk_i32 %[cnt], 64\n\t"
                        "1:\n\t"
                        "s_waitcnt vmcnt(1)\n\t"
                        "v_and_b32 %[t], 0xffff, %[pa]\n\t"
                        "v_cmp_ne_u32 vcc, %[tag], %[t]\n\t"
                        "s_cbranch_vccz 9f\n\t"
                        "global_load_dword %[pa], %[ptr], off sc0 sc1\n\t"
                        "s_waitcnt vmcnt(1)\n\t"
                        "v_and_b32 %[t], 0xffff, %[pb]\n\t"
                        "v_cmp_ne_u32 vcc, %[tag], %[t]\n\t"
                        "s_cbranch_vccz 8f\n\t"
                        "global_load_dword %[pb], %[ptr], off sc0 sc1\n\t"
                        "s_sub_u32 %[cnt], %[cnt], 1\n\t"
                        "s_cmp_lg_u32 %[cnt], 0\n\t"
                        "s_cbranch_scc1 1b\n\t"
                        "s_branch 9f\n\t"
                        "8:\n\t"
                        "s_waitcnt vmcnt(0)\n\t"          // RACE FIX: drain pa's
                        "v_mov_b32 %[pa], %[pb]\n\t"      // in-flight reload first
                        "9:\n\t"
                        : [pa]"+v"(pa), [pb]"+v"(pb), [t]"=&v"(tmp), [cnt]"=&s"(scnt)
                        : [ptr]"v"(ap), [tag]"s"(tag)
                        : "vcc", "scc", "memory");
                    if ((pa & 0xffffu) == tag) break;
                } while (--budget > 0);
                // drain any remaining in-flight poll before consuming pa
                asm volatile("s_waitcnt vmcnt(0)" ::: "memory");
                hprev[u] = __uint_as_float(pa & 0xffff0000u);
            }
            __syncthreads();   // barrier A: full h_{s-1} in hprev
            asm volatile("" :: "v"(pa), "v"(pb));
        }

        // matvec: 192 rows; 16-lane k-split, 96 FMAs/lane, 4-stage xor-reduce.
        float a0 = 0.f, a1 = 0.f, a2 = 0.f;
        #pragma unroll
        for (int m = 0; m < 8; ++m) {
            float4 h4 = hp4[m * 16 + l4];
            a0 = fmaf(wf0[m].x, h4.x, a0); a0 = fmaf(wf0[m].y, h4.y, a0);
            a0 = fmaf(wf0[m].z, h4.z, a0); a0 = fmaf(wf0[m].w, h4.w, a0);
            a1 = fmaf(wf1[m].x, h4.x, a1); a1 = fmaf(wf1[m].y, h4.y, a1);
            a1 = fmaf(wf1[m].z, h4.z, a1); a1 = fmaf(wf1[m].w, h4.w, a1);
            a2 = fmaf(wf2[m].x, h4.x, a2); a2 = fmaf(wf2[m].y, h4.y, a2);
            a2 = fmaf(wf2[m].z, h4.z, a2); a2 = fmaf(wf2[m].w, h4.w, a2);
        }
        #pragma unroll
        for (int o = 1; o < 16; o <<= 1) {
            a0 += __shfl_xor(a0, o, 64);
            a1 += __shfl_xor(a1, o, 64);
            a2 += __shfl_xor(a2, o, 64);
        }
        if (l4 == 0) {
            gsum[rr0]     = a0 + bl0;
            gsum[rr0 + 1] = a1 + bl1;
            gsum[rr0 + 2] = a2 + bl2;
        }
        __syncthreads();       // barrier B: gsum complete; all hprev reads done

        if (tid < HU) {        // gate wave: full 64 lanes, one unit each
            float gr  = gir + gsum[tid];
            float gz  = giz + gsum[HU + tid];
            float ghn = gsum[2 * HU + tid];
            float r = __builtin_amdgcn_rcpf(1.f + __expf(-gr));
            float z = __builtin_amdgcn_rcpf(1.f + __expf(-gz));
            float xt = gin + r * ghn;
            float n = 1.f - 2.f * __builtin_amdgcn_rcpf(__expf(2.f * xt) + 1.f);
            float hn = (1.f - z) * n + z * hreg;
            hreg = hn;
            // publish FIRST: {bf16 h | 16-bit tag}, 64 lanes coalesced (1 line)
            unsigned ub = __float_as_uint(hn);
            ub += 0x7fffu + ((ub >> 16) & 1u);        // RNE f32 -> bf16
            unsigned pay = (ub & 0xffff0000u) | ((unsigned)(s + 1) & 0xffffu);
            __hip_atomic_store(&hcomm[(size_t)s * NPAY + jbase + tid], pay,
                               __ATOMIC_RELAXED, __HIP_MEMORY_SCOPE_AGENT);
            int j = jbase + tid;
            hs[(size_t)s * DOUTD + j] = hn;   // full-f32 copy for the attn epilogue
            hprev[j] = hn;                    // self-publish own chunk
            if (s + 1 < TT) {                 // prefetch next step's gi
                const float* gn = gi + (size_t)(s + 1) * G3;
                gir = gn[j]; giz = gn[DOUTD + j]; gin = gn[2 * DOUTD + j];
            }
            // release the heaters at the end of the scan
            if (s == TT - 1 && b == 0 && tid == 0)
                __hip_atomic_store(done, 1u, __ATOMIC_RELAXED,
                                   __HIP_MEMORY_SCOPE_AGENT);
        }
    }
}

// ---------------- attention epilogue ----------------
__global__ void attn_kernel(const float* __restrict__ hs, const float* __restrict__ q,
                            const float* __restrict__ log_lam, float* __restrict__ out) {
    int tid = threadIdx.x;   // 512
    int wave = tid >> 6, lane = tid & 63;
    __shared__ float sc[TT];
    __shared__ float at[TT];
    __shared__ float red[8];
    __shared__ float red2[8];
    __shared__ float denom_s, mx_s;

    const float qscale = 0.04419417382415921757f;  // 1/sqrt(512)
    for (int r = wave; r < TT; r += 8) {
        float acc = 0.f;
        #pragma unroll
        for (int m = 0; m < 8; ++m) {
            int k = lane + 64 * m;
            acc = fmaf(hs[(size_t)r * DOUTD + k], q[k], acc);
        }
        for (int o = 32; o; o >>= 1) acc += __shfl_down(acc, o, 64);
        if (lane == 0) sc[r] = acc * qscale;
    }
    __syncthreads();
    float lam = fmaxf(expf(log_lam[0]), 1e-4f);
    float s_i = sc[tid] - lam * (float)(TT - 1 - tid);

    float mval = s_i;
    for (int o = 32; o; o >>= 1) mval = fmaxf(mval, __shfl_down(mval, o, 64));
    if (lane == 0) red[wave] = mval;
    __syncthreads();
    if (tid == 0) {
        float mm = red[0];
        for (int i = 1; i < 8; ++i) mm = fmaxf(mm, red[i]);
        mx_s = mm;
    }
    __syncthreads();
    float e = expf(s_i - mx_s);
    float ssum = e;
    for (int o = 32; o; o >>= 1) ssum += __shfl_down(ssum, o, 64);
    if (lane == 0) red2[wave] = ssum;
    __syncthreads();
    if (tid == 0) {
        float dsum = 0.f;
        for (int i = 0; i < 8; ++i) dsum += red2[i];
        denom_s = dsum;
    }
    __syncthreads();
    float attn = e / denom_s;
    out[DOUTD + tid] = attn;     // output 1: attn (T,)
    at[tid] = attn;
    __syncthreads();
    float acc = 0.f;
    for (int i = 0; i < TT; ++i) acc = fmaf(at[i], hs[(size_t)i * DOUTD + tid], acc);
    out[tid] = acc;              // output 0: summary (1, 512)
}

extern "C" void kernel_launch(void* const* d_in, const int* in_sizes, int n_in,
                              void* d_out, int out_size, void* d_ws, size_t ws_size,
                              hipStream_t stream) {
    const int*   idx    = (const int*)d_in[0];
    const float* timef  = (const float*)d_in[1];
    const float* emb    = (const float*)d_in[2];
    const float* latlon = (const float*)d_in[3];
    const float* lnw    = (const float*)d_in[4];
    const float* lnb    = (const float*)d_in[5];
    const float* w1     = (const float*)d_in[6];
    const float* b1     = (const float*)d_in[7];
    const float* w2     = (const float*)d_in[8];
    const float* b2     = (const float*)d_in[9];
    const float* wih    = (const float*)d_in[10];  // (1536, 256)
    const float* whh    = (const float*)d_in[11];  // (1536, 512)
    const float* bih    = (const float*)d_in[12];  // (1536,)
    const float* bhh    = (const float*)d_in[13];  // (1536,)
    const float* q      = (const float*)d_in[14];
    const float* loglam = (const float*)d_in[15];
    float* out = (float*)d_out;

    unsigned* hcomm = (unsigned*)d_ws;                       // 512*512 dwords (1 MB)
    unsigned* done  = hcomm + (size_t)TT * NPAY;             // 1 dword (padded to 64)
    float* gi = (float*)(done + 64);                         // 512*1536 = 786432
    float* hs = gi + (size_t)TT * G3;                        // 512*512 = 262144

    pre_kernel<<<TT, 512, 0, stream>>>(idx, timef, latlon, emb, lnw, lnb,
                                       w1, b1, w2, b2, wih, bih, gi, hcomm, done);
    gru_kernel<<<GB + GHEAT, 1024, 0, stream>>>(gi, whh, bhh, hs, hcomm, done);
    attn_kernel<<<1, TT, 0, stream>>>(hs, q, loglam, out);
}